// Round 1
// baseline (380.275 us; speedup 1.0000x reference)
//
#include <hip/hip_runtime.h>
#include <math.h>

constexpr int NB = 8;
constexpr int NC = 256;
constexpr int NCR = 64;
constexpr int NH = 160;
constexpr int NW = 160;
constexpr int NHW = NH * NW;           // 25600
constexpr float KEPS = 1e-4f;

constexpr int TW = 32;                 // tile width
constexpr int TH = 8;                  // tile height

// K1: y[b,d,p] = sum_c x[b,c,p] * rw[d,c]
__global__ __launch_bounds__(256) void k_reduce(const float* __restrict__ x,
                                                const float* __restrict__ rw,
                                                float* __restrict__ y) {
    const int t = threadIdx.x;
    const int blocksPerImg = NHW / 256;          // 100
    const int b = blockIdx.x / blocksPerImg;
    const int p = (blockIdx.x % blocksPerImg) * 256 + t;

    const float* xb = x + (size_t)b * NC * NHW + p;
    float acc[NCR];
#pragma unroll
    for (int d = 0; d < NCR; ++d) acc[d] = 0.f;

#pragma unroll 2
    for (int c = 0; c < NC; ++c) {
        const float v = xb[(size_t)c * NHW];
#pragma unroll
        for (int d = 0; d < NCR; ++d)
            acc[d] = fmaf(v, rw[d * NC + c], acc[d]);
    }

    float* yb = y + (size_t)b * NCR * NHW + p;
#pragma unroll
    for (int d = 0; d < NCR; ++d) yb[(size_t)d * NHW] = acc[d];
}

// K2a: pooled[b,d] = mean over spatial of y[b,d,:]
__global__ __launch_bounds__(256) void k_pool(const float* __restrict__ y,
                                              float* __restrict__ pooled) {
    const int bd = blockIdx.x;                   // 0..511
    const float* yp = y + (size_t)bd * NHW;
    float s = 0.f;
    for (int i = threadIdx.x; i < NHW; i += 256) s += yp[i];
    __shared__ float red[4];
#pragma unroll
    for (int o = 32; o > 0; o >>= 1) s += __shfl_down(s, o, 64);
    const int wave = threadIdx.x >> 6, lane = threadIdx.x & 63;
    if (lane == 0) red[wave] = s;
    __syncthreads();
    if (threadIdx.x == 0) {
        float tsum = red[0] + red[1] + red[2] + red[3];
        pooled[bd] = tsum * (1.f / (float)NHW);
    }
}

// K2b: gamma[b,d] = sigmoid(relu(pooled@w1^T+b1)@w2^T+b2)
__global__ __launch_bounds__(512) void k_gate(const float* __restrict__ pooled,
                                              const float* __restrict__ w1,
                                              const float* __restrict__ b1,
                                              const float* __restrict__ w2,
                                              const float* __restrict__ b2,
                                              float* __restrict__ gamma) {
    __shared__ float hsh[NB][16];
    const int t = threadIdx.x;
    if (t < NB * 16) {
        const int b = t / 16, j = t % 16;
        float s = b1[j];
        for (int d = 0; d < NCR; ++d) s = fmaf(pooled[b * NCR + d], w1[j * NCR + d], s);
        hsh[b][j] = fmaxf(s, 0.f);
    }
    __syncthreads();
    const int b = t / NCR, d = t % NCR;
    float s = b2[d];
#pragma unroll
    for (int j = 0; j < 16; ++j) s = fmaf(hsh[b][j], w2[d * 16 + j], s);
    gamma[t] = 1.f / (1.f + expf(-s));
}

// K3: per (b, 32x8 tile): stencil on y -> kappa -> logits -> a; out = x*(1+a)
__global__ __launch_bounds__(256) void k_fuse(const float* __restrict__ x,
                                              const float* __restrict__ y,
                                              const float* __restrict__ gamma,
                                              const float* __restrict__ fw,
                                              float* __restrict__ out) {
    __shared__ float tile[TH + 2][TW + 2];       // 10 x 34
    __shared__ float coef[NCR];

    const int b = blockIdx.z;
    const int w0 = blockIdx.x * TW, h0 = blockIdx.y * TH;
    const int t = threadIdx.x;
    const int tx = t % TW, ty = t / TW;
    const int hh = h0 + ty, ww = w0 + tx;

    if (t < NCR) coef[t] = fw[t] + gamma[b * NCR + t] * fw[NCR + t];
    __syncthreads();

    const float* yb = y + (size_t)b * NCR * NHW;
    float logit = 0.f;

    for (int c = 0; c < NCR; ++c) {
        const float* yc = yb + (size_t)c * NHW;
        for (int i = t; i < (TH + 2) * (TW + 2); i += 256) {
            const int iy = i / (TW + 2), ix = i % (TW + 2);
            const int gh = h0 + iy - 1, gw = w0 + ix - 1;
            float v = 0.f;
            if (gh >= 0 && gh < NH && gw >= 0 && gw < NW) v = yc[gh * NW + gw];
            tile[iy][ix] = v;
        }
        __syncthreads();

        const float a00 = tile[ty][tx],     a01 = tile[ty][tx + 1],     a02 = tile[ty][tx + 2];
        const float a10 = tile[ty + 1][tx], a11 = tile[ty + 1][tx + 1], a12 = tile[ty + 1][tx + 2];
        const float a20 = tile[ty + 2][tx], a21 = tile[ty + 2][tx + 1], a22 = tile[ty + 2][tx + 2];

        const float mu = (a00 + a01 + a02 + a10 + a11 + a12 + a20 + a21 + a22) * (1.f / 9.f);
        const float gx = (a00 - a02 + 2.f * (a10 - a12) + a20 - a22) * 0.125f;
        const float gy = (a00 + 2.f * a01 + a02 - a20 - 2.f * a21 - a22) * 0.125f;
        const float kappa = 1.f - fabsf(a11 - mu) / (fabsf(gx) + fabsf(gy) + KEPS);
        logit = fmaf(kappa, coef[c], logit);
        __syncthreads();
    }

    const float a = 1.f / (1.f + expf(-logit));
    const float m = 1.f + a;

    const float* xb = x + (size_t)b * NC * NHW + hh * NW + ww;
    float* ob = out + (size_t)b * NC * NHW + hh * NW + ww;
#pragma unroll 4
    for (int c = 0; c < NC; ++c)
        ob[(size_t)c * NHW] = xb[(size_t)c * NHW] * m;
}

extern "C" void kernel_launch(void* const* d_in, const int* in_sizes, int n_in,
                              void* d_out, int out_size, void* d_ws, size_t ws_size,
                              hipStream_t stream) {
    const float* x  = (const float*)d_in[0];
    const float* rw = (const float*)d_in[1];
    const float* w1 = (const float*)d_in[2];
    const float* b1 = (const float*)d_in[3];
    const float* w2 = (const float*)d_in[4];
    const float* b2 = (const float*)d_in[5];
    const float* fw = (const float*)d_in[6];
    float* out = (float*)d_out;

    float* y      = (float*)d_ws;                       // 13,107,200 floats
    float* pooled = y + (size_t)NB * NCR * NHW;         // 512 floats
    float* gamma  = pooled + NB * NCR;                  // 512 floats

    k_reduce<<<dim3(NB * (NHW / 256)), 256, 0, stream>>>(x, rw, y);
    k_pool<<<dim3(NB * NCR), 256, 0, stream>>>(y, pooled);
    k_gate<<<1, 512, 0, stream>>>(pooled, w1, b1, w2, b2, gamma);
    k_fuse<<<dim3(NW / TW, NH / TH, NB), 256, 0, stream>>>(x, y, gamma, fw, out);
}